// Round 1
// baseline (1103.137 us; speedup 1.0000x reference)
//
#include <hip/hip_runtime.h>
#include <cstdint>
#include <cstddef>

#define NPTS 2048
#define NBAT 8

__device__ __forceinline__ float4 ld4(const float* p){ return *reinterpret_cast<const float4*>(p); }
__device__ __forceinline__ void st4(float* p, float4 v){ *reinterpret_cast<float4*>(p) = v; }

__device__ __forceinline__ float blk_red_max(float v, float* red){
    #pragma unroll
    for (int o = 32; o > 0; o >>= 1) v = fmaxf(v, __shfl_xor(v, o, 64));
    int wid = threadIdx.x >> 6;
    if ((threadIdx.x & 63) == 0) red[wid] = v;
    __syncthreads();
    v = fmaxf(fmaxf(red[0], red[1]), fmaxf(red[2], red[3]));
    __syncthreads();
    return v;
}
__device__ __forceinline__ float blk_red_sum(float v, float* red){
    #pragma unroll
    for (int o = 32; o > 0; o >>= 1) v += __shfl_xor(v, o, 64);
    int wid = threadIdx.x >> 6;
    if ((threadIdx.x & 63) == 0) red[wid] = v;
    __syncthreads();
    v = red[0] + red[1] + red[2] + red[3];
    __syncthreads();
    return v;
}

// out[b,d,n] = sum_c W[d,c] * X[b,c,n] (+ bias[d])
// tile: 32 d x 128 n, BK=32, 256 threads, 4x4 micro.
template<int CIN, int COUT, bool BIAS>
__global__ __launch_bounds__(256) void lin_kernel(const float* __restrict__ W,
        const float* __restrict__ X, const float* __restrict__ bias,
        float* __restrict__ out)
{
    __shared__ float xs[32][128];
    __shared__ float wsm[32][32];   // [k][d]
    const int tid = threadIdx.x;
    const int b  = blockIdx.z;
    const int d0 = blockIdx.y * 32;
    const int n0 = blockIdx.x * 128;
    const int ng = tid & 31;        // n-group
    const int dg = tid >> 5;        // d-group 0..7
    float acc[4][4];
    #pragma unroll
    for (int i = 0; i < 4; ++i)
        #pragma unroll
        for (int j = 0; j < 4; ++j) acc[i][j] = 0.f;

    for (int k0 = 0; k0 < CIN; k0 += 32) {
        #pragma unroll
        for (int l = 0; l < 4; ++l) {           // xs: 1024 float4
            int idx = tid + 256 * l;
            int r = idx >> 5, c4 = idx & 31;
            st4(&xs[r][c4 * 4], ld4(&X[((size_t)(b * CIN + k0 + r)) * NPTS + n0 + c4 * 4]));
        }
        {
            int dl = tid >> 3, kq = tid & 7;    // wsm transpose load
            float4 wv = ld4(&W[(size_t)(d0 + dl) * CIN + k0 + kq * 4]);
            wsm[kq * 4 + 0][dl] = wv.x;
            wsm[kq * 4 + 1][dl] = wv.y;
            wsm[kq * 4 + 2][dl] = wv.z;
            wsm[kq * 4 + 3][dl] = wv.w;
        }
        __syncthreads();
        #pragma unroll
        for (int k = 0; k < 32; ++k) {
            float4 xv = ld4(&xs[k][ng * 4]);
            float4 wv = ld4(&wsm[k][dg * 4]);
            float av[4] = {wv.x, wv.y, wv.z, wv.w};
            float bv_[4] = {xv.x, xv.y, xv.z, xv.w};
            #pragma unroll
            for (int ii = 0; ii < 4; ++ii)
                #pragma unroll
                for (int jj = 0; jj < 4; ++jj)
                    acc[ii][jj] = fmaf(av[ii], bv_[jj], acc[ii][jj]);
        }
        __syncthreads();
    }
    #pragma unroll
    for (int dd = 0; dd < 4; ++dd) {
        int d = d0 + dg * 4 + dd;
        float bb = BIAS ? bias[d] : 0.f;
        float4 o;
        o.x = acc[dd][0] + bb; o.y = acc[dd][1] + bb;
        o.z = acc[dd][2] + bb; o.w = acc[dd][3] + bb;
        st4(&out[((size_t)(b * COUT + d)) * NPTS + n0 + ng * 4], o);
    }
}

// e[bl,i,j] = sum_{k<32} Q[b,k,i] * Q[b,k,j]   (batched Gram, K=32)
__global__ __launch_bounds__(256) void gram_kernel(const float* __restrict__ Q,
        float* __restrict__ att, int b0)
{
    __shared__ float qi[32][64];
    __shared__ float qj[32][64];
    const int tid = threadIdx.x;
    const int bl = blockIdx.z;
    const int b  = b0 + bl;
    const int i0 = blockIdx.y * 64;
    const int j0 = blockIdx.x * 64;
    #pragma unroll
    for (int l = 0; l < 2; ++l) {
        int idx = tid + 256 * l;
        int r = idx >> 4, c4 = idx & 15;
        st4(&qi[r][c4 * 4], ld4(&Q[((size_t)(b * 32 + r)) * NPTS + i0 + c4 * 4]));
        st4(&qj[r][c4 * 4], ld4(&Q[((size_t)(b * 32 + r)) * NPTS + j0 + c4 * 4]));
    }
    __syncthreads();
    const int jg = tid & 15, ig = tid >> 4;
    float acc[4][4];
    #pragma unroll
    for (int i = 0; i < 4; ++i)
        #pragma unroll
        for (int j = 0; j < 4; ++j) acc[i][j] = 0.f;
    #pragma unroll
    for (int k = 0; k < 32; ++k) {
        float4 iv = ld4(&qi[k][ig * 4]);
        float4 jv = ld4(&qj[k][jg * 4]);
        float av[4] = {iv.x, iv.y, iv.z, iv.w};
        float bv_[4] = {jv.x, jv.y, jv.z, jv.w};
        #pragma unroll
        for (int ii = 0; ii < 4; ++ii)
            #pragma unroll
            for (int jj = 0; jj < 4; ++jj)
                acc[ii][jj] = fmaf(av[ii], bv_[jj], acc[ii][jj]);
    }
    #pragma unroll
    for (int ii = 0; ii < 4; ++ii) {
        float4 o;
        o.x = acc[ii][0]; o.y = acc[ii][1]; o.z = acc[ii][2]; o.w = acc[ii][3];
        st4(&att[((size_t)bl * NPTS + i0 + ig * 4 + ii) * NPTS + j0 + jg * 4], o);
    }
}

// in-place row softmax over 2048 keys; one WG (256 thr) per row
__global__ __launch_bounds__(256) void softmax_kernel(float* __restrict__ att)
{
    __shared__ float red[4];
    const int tid = threadIdx.x;
    float* p = att + (size_t)blockIdx.x * NPTS;
    float v[8];
    float4 a = ld4(&p[tid * 4]);
    float4 b = ld4(&p[1024 + tid * 4]);
    v[0]=a.x; v[1]=a.y; v[2]=a.z; v[3]=a.w;
    v[4]=b.x; v[5]=b.y; v[6]=b.z; v[7]=b.w;
    float m = v[0];
    #pragma unroll
    for (int l = 1; l < 8; ++l) m = fmaxf(m, v[l]);
    m = blk_red_max(m, red);
    float s = 0.f;
    #pragma unroll
    for (int l = 0; l < 8; ++l) { v[l] = __expf(v[l] - m); s += v[l]; }
    s = blk_red_sum(s, red);
    float inv = 1.f / s;
    float4 o0, o1;
    o0.x=v[0]*inv; o0.y=v[1]*inv; o0.z=v[2]*inv; o0.w=v[3]*inv;
    o1.x=v[4]*inv; o1.y=v[5]*inv; o1.z=v[6]*inv; o1.w=v[7]*inv;
    st4(&p[tid * 4], o0);
    st4(&p[1024 + tid * 4], o1);
}

// partial column sums: grid.x = 8 j-tiles * 16 i-chunks, grid.y = nb
__global__ __launch_bounds__(256) void colsum_part_kernel(const float* __restrict__ att,
        float* __restrict__ part)
{
    const int jt = blockIdx.x & 7;
    const int ic = blockIdx.x >> 3;
    const int bl = blockIdx.y;
    const int j = jt * 256 + threadIdx.x;
    const float* p = att + ((size_t)bl * NPTS + ic * 128) * NPTS + j;
    float s = 0.f;
    #pragma unroll 4
    for (int i = 0; i < 128; ++i) s += p[(size_t)i * NPTS];
    part[((size_t)bl * 16 + ic) * NPTS + j] = s;
}

__global__ __launch_bounds__(256) void colsum_fin_kernel(const float* __restrict__ part,
        float* __restrict__ invcol, int b0)
{
    const int bl = blockIdx.y;
    const int j = blockIdx.x * 256 + threadIdx.x;
    float s = 0.f;
    #pragma unroll
    for (int ic = 0; ic < 16; ++ic) s += part[((size_t)bl * 16 + ic) * NPTS + j];
    invcol[(size_t)(b0 + bl) * NPTS + j] = 1.f / (1e-9f + s);
}

// T[b,c,j] = H[b,c,j] - (sum_i V[b,c,i] * att[bl,i,j]) * invcol[b,j]
// tile 64c x 64j, BK=32, 4x4 micro
__global__ __launch_bounds__(256) void xr_kernel(const float* __restrict__ V,
        const float* __restrict__ att, const float* __restrict__ invcol,
        const float* __restrict__ H, float* __restrict__ T, int b0)
{
    __shared__ float as_[32][64];   // [k][c]
    __shared__ float bs_[32][64];   // [k][j]
    const int tid = threadIdx.x;
    const int bl = blockIdx.z;
    const int b  = b0 + bl;
    const int c0 = blockIdx.y * 64;
    const int j0 = blockIdx.x * 64;
    const int jg = tid & 15, cg = tid >> 4;
    float acc[4][4];
    #pragma unroll
    for (int i = 0; i < 4; ++i)
        #pragma unroll
        for (int j = 0; j < 4; ++j) acc[i][j] = 0.f;

    for (int k0 = 0; k0 < NPTS; k0 += 32) {
        #pragma unroll
        for (int l = 0; l < 2; ++l) {           // as_: transpose V tile
            int idx = tid + 256 * l;
            int cl = idx >> 3, kq = idx & 7;
            float4 vv = ld4(&V[((size_t)(b * 128 + c0 + cl)) * NPTS + k0 + kq * 4]);
            as_[kq * 4 + 0][cl] = vv.x;
            as_[kq * 4 + 1][cl] = vv.y;
            as_[kq * 4 + 2][cl] = vv.z;
            as_[kq * 4 + 3][cl] = vv.w;
        }
        #pragma unroll
        for (int l = 0; l < 2; ++l) {           // bs_: att rows direct
            int idx = tid + 256 * l;
            int r = idx >> 4, c4 = idx & 15;
            st4(&bs_[r][c4 * 4], ld4(&att[((size_t)bl * NPTS + k0 + r) * NPTS + j0 + c4 * 4]));
        }
        __syncthreads();
        #pragma unroll
        for (int k = 0; k < 32; ++k) {
            float4 av4 = ld4(&as_[k][cg * 4]);
            float4 bv4 = ld4(&bs_[k][jg * 4]);
            float av[4] = {av4.x, av4.y, av4.z, av4.w};
            float bv_[4] = {bv4.x, bv4.y, bv4.z, bv4.w};
            #pragma unroll
            for (int ii = 0; ii < 4; ++ii)
                #pragma unroll
                for (int jj = 0; jj < 4; ++jj)
                    acc[ii][jj] = fmaf(av[ii], bv_[jj], acc[ii][jj]);
        }
        __syncthreads();
    }
    float4 ic4 = ld4(&invcol[(size_t)b * NPTS + j0 + jg * 4]);
    float icv[4] = {ic4.x, ic4.y, ic4.z, ic4.w};
    #pragma unroll
    for (int ci = 0; ci < 4; ++ci) {
        int c = c0 + cg * 4 + ci;
        size_t base = ((size_t)(b * 128 + c)) * NPTS + j0 + jg * 4;
        float4 hv = ld4(&H[base]);
        float4 o;
        o.x = hv.x - acc[ci][0] * icv[0];
        o.y = hv.y - acc[ci][1] * icv[1];
        o.z = hv.z - acc[ci][2] * icv[2];
        o.w = hv.w - acc[ci][3] * icv[3];
        st4(&T[base], o);
    }
}

// per-channel mean/invstd over (B, N); one WG per channel
__global__ __launch_bounds__(256) void bn_stats_kernel(const float* __restrict__ X,
        int C, float* __restrict__ stats)
{
    __shared__ float red[4];
    const int c = blockIdx.x;
    const int tid = threadIdx.x;
    float s = 0.f, s2 = 0.f;
    for (int b = 0; b < NBAT; ++b) {
        const float* p = &X[((size_t)(b * C + c)) * NPTS];
        #pragma unroll
        for (int l = 0; l < 2; ++l) {
            float4 v = ld4(&p[(tid + 256 * l) * 4]);
            s  += v.x + v.y + v.z + v.w;
            s2 += v.x * v.x + v.y * v.y + v.z * v.z + v.w * v.w;
        }
    }
    s  = blk_red_sum(s, red);
    s2 = blk_red_sum(s2, red);
    if (tid == 0) {
        const float invn = 1.f / (NBAT * NPTS);
        float mean = s * invn;
        float var = s2 * invn - mean * mean;
        stats[c] = mean;
        stats[C + c] = rsqrtf(var + 1e-5f);
    }
}

// out = relu(g*(x-mean)*invstd + beta); grid (NPTS/1024, B*C)
__global__ __launch_bounds__(256) void bn_apply_kernel(const float* __restrict__ X,
        const float* __restrict__ g, const float* __restrict__ beta,
        const float* __restrict__ stats, int C, float* __restrict__ out)
{
    const int bc = blockIdx.y;
    const int c = bc % C;
    const int n = blockIdx.x * 1024 + threadIdx.x * 4;
    const float mean = stats[c], is = stats[C + c];
    const float ga = g[c] * is;
    const float be = beta[c] - mean * ga;
    float4 v = ld4(&X[(size_t)bc * NPTS + n]);
    float4 o;
    o.x = fmaxf(fmaf(ga, v.x, be), 0.f);
    o.y = fmaxf(fmaf(ga, v.y, be), 0.f);
    o.z = fmaxf(fmaf(ga, v.z, be), 0.f);
    o.w = fmaxf(fmaf(ga, v.w, be), 0.f);
    st4(&out[(size_t)bc * NPTS + n], o);
}

// h_new = h + relu(bn(y)); write h and out slice; C=128
__global__ __launch_bounds__(256) void bn_res_kernel(const float* __restrict__ Y,
        const float* __restrict__ g, const float* __restrict__ beta,
        const float* __restrict__ stats, float* __restrict__ H,
        float* __restrict__ out, int blk)
{
    const int bc = blockIdx.y;
    const int c = bc & 127;
    const int b = bc >> 7;
    const int n = blockIdx.x * 1024 + threadIdx.x * 4;
    const float mean = stats[c], is = stats[128 + c];
    const float ga = g[c] * is;
    const float be = beta[c] - mean * ga;
    float4 yv = ld4(&Y[(size_t)bc * NPTS + n]);
    float4 hv = ld4(&H[(size_t)bc * NPTS + n]);
    float4 o;
    o.x = hv.x + fmaxf(fmaf(ga, yv.x, be), 0.f);
    o.y = hv.y + fmaxf(fmaf(ga, yv.y, be), 0.f);
    o.z = hv.z + fmaxf(fmaf(ga, yv.z, be), 0.f);
    o.w = hv.w + fmaxf(fmaf(ga, yv.w, be), 0.f);
    st4(&H[(size_t)bc * NPTS + n], o);
    st4(&out[((size_t)(b * 512 + blk * 128 + c)) * NPTS + n], o);
}

extern "C" void kernel_launch(void* const* d_in, const int* in_sizes, int n_in,
                              void* d_out, int out_size, void* d_ws, size_t ws_size,
                              hipStream_t stream)
{
    const float* x   = (const float*)d_in[0];
    const float* W1  = (const float*)d_in[1];
    const float* g1  = (const float*)d_in[2];
    const float* b1  = (const float*)d_in[3];
    const float* W2  = (const float*)d_in[4];
    const float* g2  = (const float*)d_in[5];
    const float* b2  = (const float*)d_in[6];
    const float* Wqk = (const float*)d_in[7];
    const float* Wv  = (const float*)d_in[8];
    const float* bv  = (const float*)d_in[9];
    const float* Wt  = (const float*)d_in[10];
    const float* bt  = (const float*)d_in[11];
    const float* gn  = (const float*)d_in[12];
    const float* bnb = (const float*)d_in[13];
    float* out = (float*)d_out;

    float* ws = (float*)d_ws;
    size_t off = 0;
    auto alloc = [&](size_t n) { float* p = ws + off; off += n; return p; };
    float* h      = alloc((size_t)NBAT * 128 * NPTS);
    float* q      = alloc((size_t)NBAT * 32 * NPTS);
    float* v      = alloc((size_t)NBAT * 128 * NPTS);
    float* t      = alloc((size_t)NBAT * 128 * NPTS);
    float* y      = alloc((size_t)NBAT * 128 * NPTS);
    float* stats  = alloc(256);
    float* invcol = alloc((size_t)NBAT * NPTS);
    float* part   = alloc((size_t)NBAT * 16 * NPTS);
    float* att    = ws + off;
    size_t totf = ws_size / sizeof(float);
    size_t rem = (totf > off) ? (totf - off) : 0;
    int chunk = (int)(rem / ((size_t)NPTS * NPTS));
    if (chunk > NBAT) chunk = NBAT;
    if (chunk < 1) chunk = 1;

    // stem: h = relu(bn(W2 @ relu(bn(W1 @ x))))
    lin_kernel<64, 64, false><<<dim3(16, 2, NBAT), 256, 0, stream>>>(W1, x, nullptr, y);
    bn_stats_kernel<<<64, 256, 0, stream>>>(y, 64, stats);
    bn_apply_kernel<<<dim3(2, NBAT * 64), 256, 0, stream>>>(y, g1, b1, stats, 64, t);
    lin_kernel<64, 128, false><<<dim3(16, 4, NBAT), 256, 0, stream>>>(W2, t, nullptr, y);
    bn_stats_kernel<<<128, 256, 0, stream>>>(y, 128, stats);
    bn_apply_kernel<<<dim3(2, NBAT * 128), 256, 0, stream>>>(y, g2, b2, stats, 128, h);

    for (int blk = 0; blk < 4; ++blk) {
        lin_kernel<128, 32, false><<<dim3(16, 1, NBAT), 256, 0, stream>>>(
            Wqk + (size_t)blk * 32 * 128, h, nullptr, q);
        lin_kernel<128, 128, true><<<dim3(16, 4, NBAT), 256, 0, stream>>>(
            Wv + (size_t)blk * 128 * 128, h, bv + blk * 128, v);
        for (int b0 = 0; b0 < NBAT; b0 += chunk) {
            int nb = NBAT - b0 < chunk ? NBAT - b0 : chunk;
            gram_kernel<<<dim3(32, 32, nb), 256, 0, stream>>>(q, att, b0);
            softmax_kernel<<<nb * NPTS, 256, 0, stream>>>(att);
            colsum_part_kernel<<<dim3(128, nb), 256, 0, stream>>>(att, part);
            colsum_fin_kernel<<<dim3(8, nb), 256, 0, stream>>>(part, invcol, b0);
            xr_kernel<<<dim3(32, 2, nb), 256, 0, stream>>>(v, att, invcol, h, t, b0);
        }
        lin_kernel<128, 128, true><<<dim3(16, 4, NBAT), 256, 0, stream>>>(
            Wt + (size_t)blk * 128 * 128, t, bt + blk * 128, y);
        bn_stats_kernel<<<128, 256, 0, stream>>>(y, 128, stats);
        bn_res_kernel<<<dim3(2, NBAT * 128), 256, 0, stream>>>(
            y, gn + blk * 128, bnb + blk * 128, stats, h, out, blk);
    }
}

// Round 2
// 579.149 us; speedup vs baseline: 1.9048x; 1.9048x over previous
//
#include <hip/hip_runtime.h>
#include <cstdint>
#include <cstddef>

#define NPTS 2048
#define NBAT 8

typedef unsigned long long ull;
typedef __attribute__((ext_vector_type(8))) short bf16x8;
typedef __attribute__((ext_vector_type(4))) float f32x4;

__device__ __forceinline__ float4 ld4(const float* p){ return *reinterpret_cast<const float4*>(p); }
__device__ __forceinline__ void st4(float* p, float4 v){ *reinterpret_cast<float4*>(p) = v; }
__device__ __forceinline__ unsigned short f2bf(float f){
    unsigned int u = __float_as_uint(f);
    u += 0x7FFFu + ((u >> 16) & 1u);
    return (unsigned short)(u >> 16);
}

__device__ __forceinline__ float blk_red_max(float v, float* red){
    #pragma unroll
    for (int o = 32; o > 0; o >>= 1) v = fmaxf(v, __shfl_xor(v, o, 64));
    int wid = threadIdx.x >> 6;
    if ((threadIdx.x & 63) == 0) red[wid] = v;
    __syncthreads();
    v = fmaxf(fmaxf(red[0], red[1]), fmaxf(red[2], red[3]));
    __syncthreads();
    return v;
}
__device__ __forceinline__ float blk_red_sum(float v, float* red){
    #pragma unroll
    for (int o = 32; o > 0; o >>= 1) v += __shfl_xor(v, o, 64);
    int wid = threadIdx.x >> 6;
    if ((threadIdx.x & 63) == 0) red[wid] = v;
    __syncthreads();
    v = red[0] + red[1] + red[2] + red[3];
    __syncthreads();
    return v;
}

// out[b,d,n] = sum_c W[d,c] * X[b,c,n] (+ bias[d]); optional bf16 output
template<int CIN, int COUT, bool BIAS, bool OBF>
__global__ __launch_bounds__(256) void lin_kernel(const float* __restrict__ W,
        const float* __restrict__ X, const float* __restrict__ bias,
        void* __restrict__ outv)
{
    __shared__ float xs[32][128];
    __shared__ float wsm[32][32];   // [k][d]
    const int tid = threadIdx.x;
    const int b  = blockIdx.z;
    const int d0 = blockIdx.y * 32;
    const int n0 = blockIdx.x * 128;
    const int ng = tid & 31;
    const int dg = tid >> 5;
    float acc[4][4];
    #pragma unroll
    for (int i = 0; i < 4; ++i)
        #pragma unroll
        for (int j = 0; j < 4; ++j) acc[i][j] = 0.f;

    for (int k0 = 0; k0 < CIN; k0 += 32) {
        #pragma unroll
        for (int l = 0; l < 4; ++l) {
            int idx = tid + 256 * l;
            int r = idx >> 5, c4 = idx & 31;
            st4(&xs[r][c4 * 4], ld4(&X[((size_t)(b * CIN + k0 + r)) * NPTS + n0 + c4 * 4]));
        }
        {
            int dl = tid >> 3, kq = tid & 7;
            float4 wv = ld4(&W[(size_t)(d0 + dl) * CIN + k0 + kq * 4]);
            wsm[kq * 4 + 0][dl] = wv.x;
            wsm[kq * 4 + 1][dl] = wv.y;
            wsm[kq * 4 + 2][dl] = wv.z;
            wsm[kq * 4 + 3][dl] = wv.w;
        }
        __syncthreads();
        #pragma unroll
        for (int k = 0; k < 32; ++k) {
            float4 xv = ld4(&xs[k][ng * 4]);
            float4 wv = ld4(&wsm[k][dg * 4]);
            float av[4] = {wv.x, wv.y, wv.z, wv.w};
            float bv_[4] = {xv.x, xv.y, xv.z, xv.w};
            #pragma unroll
            for (int ii = 0; ii < 4; ++ii)
                #pragma unroll
                for (int jj = 0; jj < 4; ++jj)
                    acc[ii][jj] = fmaf(av[ii], bv_[jj], acc[ii][jj]);
        }
        __syncthreads();
    }
    #pragma unroll
    for (int dd = 0; dd < 4; ++dd) {
        int d = d0 + dg * 4 + dd;
        float bb = BIAS ? bias[d] : 0.f;
        size_t base = ((size_t)(b * COUT + d)) * NPTS + n0 + ng * 4;
        if (OBF) {
            unsigned short* ob = (unsigned short*)outv;
            ushort4 o;
            o.x = f2bf(acc[dd][0] + bb); o.y = f2bf(acc[dd][1] + bb);
            o.z = f2bf(acc[dd][2] + bb); o.w = f2bf(acc[dd][3] + bb);
            *reinterpret_cast<ushort4*>(&ob[base]) = o;
        } else {
            float* out = (float*)outv;
            float4 o;
            o.x = acc[dd][0] + bb; o.y = acc[dd][1] + bb;
            o.z = acc[dd][2] + bb; o.w = acc[dd][3] + bb;
            st4(&out[base], o);
        }
    }
}

// e[bl,i,j] = sum_{k<32} Q[b,k,i] * Q[b,k,j]   (batched Gram, K=32)
__global__ __launch_bounds__(256) void gram_kernel(const float* __restrict__ Q,
        float* __restrict__ att, int b0)
{
    __shared__ float qi[32][64];
    __shared__ float qj[32][64];
    const int tid = threadIdx.x;
    const int bl = blockIdx.z;
    const int b  = b0 + bl;
    const int i0 = blockIdx.y * 64;
    const int j0 = blockIdx.x * 64;
    #pragma unroll
    for (int l = 0; l < 2; ++l) {
        int idx = tid + 256 * l;
        int r = idx >> 4, c4 = idx & 15;
        st4(&qi[r][c4 * 4], ld4(&Q[((size_t)(b * 32 + r)) * NPTS + i0 + c4 * 4]));
        st4(&qj[r][c4 * 4], ld4(&Q[((size_t)(b * 32 + r)) * NPTS + j0 + c4 * 4]));
    }
    __syncthreads();
    const int jg = tid & 15, ig = tid >> 4;
    float acc[4][4];
    #pragma unroll
    for (int i = 0; i < 4; ++i)
        #pragma unroll
        for (int j = 0; j < 4; ++j) acc[i][j] = 0.f;
    #pragma unroll
    for (int k = 0; k < 32; ++k) {
        float4 iv = ld4(&qi[k][ig * 4]);
        float4 jv = ld4(&qj[k][jg * 4]);
        float av[4] = {iv.x, iv.y, iv.z, iv.w};
        float bv_[4] = {jv.x, jv.y, jv.z, jv.w};
        #pragma unroll
        for (int ii = 0; ii < 4; ++ii)
            #pragma unroll
            for (int jj = 0; jj < 4; ++jj)
                acc[ii][jj] = fmaf(av[ii], bv_[jj], acc[ii][jj]);
    }
    #pragma unroll
    for (int ii = 0; ii < 4; ++ii) {
        float4 o;
        o.x = acc[ii][0]; o.y = acc[ii][1]; o.z = acc[ii][2]; o.w = acc[ii][3];
        st4(&att[((size_t)bl * NPTS + i0 + ig * 4 + ii) * NPTS + j0 + jg * 4], o);
    }
}

// per-row softmax stats of e: rowm[b,i] = max_j e, rowinv[b,i] = 1/sum_j exp(e-max)
__global__ __launch_bounds__(256) void rowstats_kernel(const float* __restrict__ E,
        float* __restrict__ rowm, float* __restrict__ rowinv, int b0)
{
    __shared__ float red[4];
    const int tid = threadIdx.x;
    const float* p = E + (size_t)blockIdx.x * NPTS;
    float v[8];
    float4 a = ld4(&p[tid * 4]);
    float4 bq = ld4(&p[1024 + tid * 4]);
    v[0]=a.x; v[1]=a.y; v[2]=a.z; v[3]=a.w;
    v[4]=bq.x; v[5]=bq.y; v[6]=bq.z; v[7]=bq.w;
    float m = v[0];
    #pragma unroll
    for (int l = 1; l < 8; ++l) m = fmaxf(m, v[l]);
    m = blk_red_max(m, red);
    float s = 0.f;
    #pragma unroll
    for (int l = 0; l < 8; ++l) s += __expf(v[l] - m);
    s = blk_red_sum(s, red);
    if (tid == 0) {
        int b = b0 + (blockIdx.x >> 11);
        int i = blockIdx.x & 2047;
        rowm[(size_t)b * NPTS + i] = m;
        rowinv[(size_t)b * NPTS + i] = 1.f / s;
    }
}

// T[b,c,j] = H[b,c,j] - (sum_i V[b,c,i] * attT[j,i]) / (eps + colsum_j)
// attT[j,i] = exp(e[j,i] - rowm[i]) * rowinv[i]   (valid since e is symmetric)
// tile: 128 c x 64 j, full K=2048; MFMA 16x16x32 bf16; 4 waves (2c x 2j)
__global__ __launch_bounds__(256) void xr_mfma_kernel(
        const unsigned short* __restrict__ V,   // [8][128][2048] bf16
        const float* __restrict__ E,            // [nb][2048][2048] fp32
        const float* __restrict__ rowm, const float* __restrict__ rowinv,
        const float* __restrict__ H, float* __restrict__ T, int b0)
{
    __shared__ unsigned short Alds[128 * 64];   // [c][64 k] swizzled rows (128B)
    __shared__ unsigned short Blds[64 * 64];    // [j][64 k] swizzled rows (128B)
    __shared__ float colsum_lds[64];
    const int tid = threadIdx.x;
    const int bl = blockIdx.z;
    const int b  = b0 + bl;
    const int j0 = blockIdx.x * 64;
    const int lane = tid & 63;
    const int w = tid >> 6;
    const int cb = (w >> 1) * 64;   // wave c-base
    const int jb = (w & 1) * 32;    // wave j-base (local)
    f32x4 acc[4][2];
    #pragma unroll
    for (int i = 0; i < 4; ++i)
        #pragma unroll
        for (int j = 0; j < 2; ++j) acc[i][j] = (f32x4){0.f, 0.f, 0.f, 0.f};
    float csum[4] = {0.f, 0.f, 0.f, 0.f};

    for (int i0 = 0; i0 < NPTS; i0 += 64) {
        // stage A: v[c][i0..i0+63] bf16, 128 rows x 128B, XOR-swizzled
        #pragma unroll
        for (int it = 0; it < 4; ++it) {
            int idx = tid + 256 * it;
            int c = idx >> 3, slot = idx & 7;
            int sl = slot ^ (c & 7);
            float4 av = ld4((const float*)(V + ((size_t)(b * 128 + c)) * NPTS + i0 + slot * 8));
            *reinterpret_cast<float4*>(&Alds[c * 64 + sl * 8]) = av;
        }
        // stage B: attT[j][i] = exp(e[j0+j][i]-m_i)*inv_i  -> bf16, swizzled; accumulate colsum
        #pragma unroll
        for (int it = 0; it < 4; ++it) {
            int idx = tid + 256 * it;
            int j = idx >> 4, io = (idx & 15) * 4;
            float4 ev = ld4(&E[((size_t)bl * NPTS + j0 + j) * NPTS + i0 + io]);
            float4 mv = ld4(&rowm[(size_t)b * NPTS + i0 + io]);
            float4 sv = ld4(&rowinv[(size_t)b * NPTS + i0 + io]);
            float p0 = __expf(ev.x - mv.x) * sv.x;
            float p1 = __expf(ev.y - mv.y) * sv.y;
            float p2 = __expf(ev.z - mv.z) * sv.z;
            float p3 = __expf(ev.w - mv.w) * sv.w;
            csum[it] += p0 + p1 + p2 + p3;
            int sl = (io >> 3) ^ (j & 7);
            ull pk = (ull)f2bf(p0) | ((ull)f2bf(p1) << 16) |
                     ((ull)f2bf(p2) << 32) | ((ull)f2bf(p3) << 48);
            *reinterpret_cast<ull*>(&Blds[j * 64 + sl * 8 + (io & 7)]) = pk;
        }
        __syncthreads();
        #pragma unroll
        for (int ks = 0; ks < 2; ++ks) {
            bf16x8 bfr[2];
            #pragma unroll
            for (int fb = 0; fb < 2; ++fb) {
                int j = jb + fb * 16 + (lane & 15);
                int sl = (ks * 4 + (lane >> 4)) ^ (j & 7);
                bfr[fb] = *reinterpret_cast<bf16x8*>(&Blds[j * 64 + sl * 8]);
            }
            #pragma unroll
            for (int fa = 0; fa < 4; ++fa) {
                int c = cb + fa * 16 + (lane & 15);
                int sl = (ks * 4 + (lane >> 4)) ^ (c & 7);
                bf16x8 afr = *reinterpret_cast<bf16x8*>(&Alds[c * 64 + sl * 8]);
                acc[fa][0] = __builtin_amdgcn_mfma_f32_16x16x32_bf16(afr, bfr[0], acc[fa][0], 0, 0, 0);
                acc[fa][1] = __builtin_amdgcn_mfma_f32_16x16x32_bf16(afr, bfr[1], acc[fa][1], 0, 0, 0);
            }
        }
        __syncthreads();
    }
    // reduce colsum: threads 16g..16g+15 hold partials for j = g + 16*it
    #pragma unroll
    for (int it = 0; it < 4; ++it) {
        float vsum = csum[it];
        vsum += __shfl_xor(vsum, 1, 64);
        vsum += __shfl_xor(vsum, 2, 64);
        vsum += __shfl_xor(vsum, 4, 64);
        vsum += __shfl_xor(vsum, 8, 64);
        if ((tid & 15) == 0) colsum_lds[(tid >> 4) + 16 * it] = vsum;
    }
    __syncthreads();
    // epilogue: T = H - acc * inv(colsum)
    #pragma unroll
    for (int fb = 0; fb < 2; ++fb) {
        int jl = jb + fb * 16 + (lane & 15);
        float inv = 1.f / (1e-9f + colsum_lds[jl]);
        int jg_ = j0 + jl;
        #pragma unroll
        for (int fa = 0; fa < 4; ++fa) {
            #pragma unroll
            for (int r = 0; r < 4; ++r) {
                int c = cb + fa * 16 + (lane >> 4) * 4 + r;
                size_t base = ((size_t)(b * 128 + c)) * NPTS + jg_;
                T[base] = H[base] - acc[fa][fb][r] * inv;
            }
        }
    }
}

// per-channel mean/invstd over (B, N); one WG per channel
__global__ __launch_bounds__(256) void bn_stats_kernel(const float* __restrict__ X,
        int C, float* __restrict__ stats)
{
    __shared__ float red[4];
    const int c = blockIdx.x;
    const int tid = threadIdx.x;
    float s = 0.f, s2 = 0.f;
    for (int b = 0; b < NBAT; ++b) {
        const float* p = &X[((size_t)(b * C + c)) * NPTS];
        #pragma unroll
        for (int l = 0; l < 2; ++l) {
            float4 v = ld4(&p[(tid + 256 * l) * 4]);
            s  += v.x + v.y + v.z + v.w;
            s2 += v.x * v.x + v.y * v.y + v.z * v.z + v.w * v.w;
        }
    }
    s  = blk_red_sum(s, red);
    s2 = blk_red_sum(s2, red);
    if (tid == 0) {
        const float invn = 1.f / (NBAT * NPTS);
        float mean = s * invn;
        float var = s2 * invn - mean * mean;
        stats[c] = mean;
        stats[C + c] = rsqrtf(var + 1e-5f);
    }
}

__global__ __launch_bounds__(256) void bn_apply_kernel(const float* __restrict__ X,
        const float* __restrict__ g, const float* __restrict__ beta,
        const float* __restrict__ stats, int C, float* __restrict__ out)
{
    const int bc = blockIdx.y;
    const int c = bc % C;
    const int n = blockIdx.x * 1024 + threadIdx.x * 4;
    const float mean = stats[c], is = stats[C + c];
    const float ga = g[c] * is;
    const float be = beta[c] - mean * ga;
    float4 v = ld4(&X[(size_t)bc * NPTS + n]);
    float4 o;
    o.x = fmaxf(fmaf(ga, v.x, be), 0.f);
    o.y = fmaxf(fmaf(ga, v.y, be), 0.f);
    o.z = fmaxf(fmaf(ga, v.z, be), 0.f);
    o.w = fmaxf(fmaf(ga, v.w, be), 0.f);
    st4(&out[(size_t)bc * NPTS + n], o);
}

__global__ __launch_bounds__(256) void bn_res_kernel(const float* __restrict__ Y,
        const float* __restrict__ g, const float* __restrict__ beta,
        const float* __restrict__ stats, float* __restrict__ H,
        float* __restrict__ out, int blk)
{
    const int bc = blockIdx.y;
    const int c = bc & 127;
    const int b = bc >> 7;
    const int n = blockIdx.x * 1024 + threadIdx.x * 4;
    const float mean = stats[c], is = stats[128 + c];
    const float ga = g[c] * is;
    const float be = beta[c] - mean * ga;
    float4 yv = ld4(&Y[(size_t)bc * NPTS + n]);
    float4 hv = ld4(&H[(size_t)bc * NPTS + n]);
    float4 o;
    o.x = hv.x + fmaxf(fmaf(ga, yv.x, be), 0.f);
    o.y = hv.y + fmaxf(fmaf(ga, yv.y, be), 0.f);
    o.z = hv.z + fmaxf(fmaf(ga, yv.z, be), 0.f);
    o.w = hv.w + fmaxf(fmaf(ga, yv.w, be), 0.f);
    st4(&H[(size_t)bc * NPTS + n], o);
    st4(&out[((size_t)(b * 512 + blk * 128 + c)) * NPTS + n], o);
}

extern "C" void kernel_launch(void* const* d_in, const int* in_sizes, int n_in,
                              void* d_out, int out_size, void* d_ws, size_t ws_size,
                              hipStream_t stream)
{
    const float* x   = (const float*)d_in[0];
    const float* W1  = (const float*)d_in[1];
    const float* g1  = (const float*)d_in[2];
    const float* b1  = (const float*)d_in[3];
    const float* W2  = (const float*)d_in[4];
    const float* g2  = (const float*)d_in[5];
    const float* b2  = (const float*)d_in[6];
    const float* Wqk = (const float*)d_in[7];
    const float* Wv  = (const float*)d_in[8];
    const float* bv  = (const float*)d_in[9];
    const float* Wt  = (const float*)d_in[10];
    const float* bt  = (const float*)d_in[11];
    const float* gn  = (const float*)d_in[12];
    const float* bnb = (const float*)d_in[13];
    float* out = (float*)d_out;

    float* ws = (float*)d_ws;
    size_t off = 0;
    auto alloc = [&](size_t n) { float* p = ws + off; off += n; return p; };
    float* h      = alloc((size_t)NBAT * 128 * NPTS);
    float* q      = alloc((size_t)NBAT * 32 * NPTS);
    float* t      = alloc((size_t)NBAT * 128 * NPTS);
    float* y      = alloc((size_t)NBAT * 128 * NPTS);
    float* stats  = alloc(256);
    float* rowm   = alloc((size_t)NBAT * NPTS);
    float* rowinv = alloc((size_t)NBAT * NPTS);
    unsigned short* vb = (unsigned short*)alloc((size_t)NBAT * 128 * NPTS / 2);
    float* e      = ws + off;
    size_t totf = ws_size / sizeof(float);
    size_t rem = (totf > off) ? (totf - off) : 0;
    int chunk = (int)(rem / ((size_t)NPTS * NPTS));
    if (chunk > NBAT) chunk = NBAT;
    if (chunk < 1) chunk = 1;

    // stem: h = relu(bn(W2 @ relu(bn(W1 @ x))))
    lin_kernel<64, 64, false, false><<<dim3(16, 2, NBAT), 256, 0, stream>>>(W1, x, nullptr, y);
    bn_stats_kernel<<<64, 256, 0, stream>>>(y, 64, stats);
    bn_apply_kernel<<<dim3(2, NBAT * 64), 256, 0, stream>>>(y, g1, b1, stats, 64, t);
    lin_kernel<64, 128, false, false><<<dim3(16, 4, NBAT), 256, 0, stream>>>(W2, t, nullptr, y);
    bn_stats_kernel<<<128, 256, 0, stream>>>(y, 128, stats);
    bn_apply_kernel<<<dim3(2, NBAT * 128), 256, 0, stream>>>(y, g2, b2, stats, 128, h);

    for (int blk = 0; blk < 4; ++blk) {
        lin_kernel<128, 32, false, false><<<dim3(16, 1, NBAT), 256, 0, stream>>>(
            Wqk + (size_t)blk * 32 * 128, h, nullptr, q);
        lin_kernel<128, 128, true, true><<<dim3(16, 4, NBAT), 256, 0, stream>>>(
            Wv + (size_t)blk * 128 * 128, h, bv + blk * 128, vb);
        for (int b0 = 0; b0 < NBAT; b0 += chunk) {
            int nb = NBAT - b0 < chunk ? NBAT - b0 : chunk;
            gram_kernel<<<dim3(32, 32, nb), 256, 0, stream>>>(q, e, b0);
            rowstats_kernel<<<nb * NPTS, 256, 0, stream>>>(e, rowm, rowinv, b0);
            xr_mfma_kernel<<<dim3(32, 1, nb), 256, 0, stream>>>(vb, e, rowm, rowinv, h, t, b0);
        }
        lin_kernel<128, 128, true, false><<<dim3(16, 4, NBAT), 256, 0, stream>>>(
            Wt + (size_t)blk * 128 * 128, t, bt + blk * 128, y);
        bn_stats_kernel<<<128, 256, 0, stream>>>(y, 128, stats);
        bn_res_kernel<<<dim3(2, NBAT * 128), 256, 0, stream>>>(
            y, gn + blk * 128, bnb + blk * 128, stats, h, out, blk);
    }
}